// Round 5
// baseline (283.457 us; speedup 1.0000x reference)
//
#include <hip/hip_runtime.h>
#include <hip/hip_bf16.h>

// ConvIntrinsic: gather+barycentric -> patch-operator -> 8 rotated folds.
// Identity: interp[r,a,(rho,alpha)] depends only on (a-alpha)&7, so all 8
// rotations share ONE 256-column B (2.6 MB, L2-resident); the rot-roll is a
// wave-uniform q-permute on A's k-offset. GEMM: virtual M=(rot,slab), N=256,
// K=5120 bf16 MFMA, XCD-swizzled (one sig slab + whole B per XCD L2).
//
// R5: non-GEMM budget attack. Prep rebuilt as 1628 fat blocks (was 30,128
// tiny ones; dispatch-overhead suspect); split-K dropped -> epilogue fused
// into GEMM (no 98 MB partials, ws 163->64 MB, 2 kernels/iter not 3).

#define N_PTS 6000
#define RR 5
#define AA 8
#define FF 128
#define OO 128
#define QQ 40          // R*A
#define KD 5120        // QQ*FF  (GEMM K)
#define NCOL 256       // 2 k * 128 o (GEMM N, single-rot B)
#define SIG_BLOCKS 1500          // 4 points per block
#define W2_BLOCKS (NCOL / 2)     // 2 j per block

typedef __bf16 bf16_t;
typedef __bf16 bf16x4 __attribute__((ext_vector_type(4)));
typedef __bf16 bf16x8 __attribute__((ext_vector_type(8)));
typedef float f32x4 __attribute__((ext_vector_type(4)));

#define GLOAD_LDS16(g, l)                                              \
  __builtin_amdgcn_global_load_lds(                                    \
      (const __attribute__((address_space(1))) void*)(g),              \
      (__attribute__((address_space(3))) void*)(l), 16, 0, 0)

// ------------------------------------------------------------- prep pass
// blocks [0,1500): sig for 4 points each. 256 thr = 8 q-slots x 32 f-lanes;
//   bary staged to LDS first so all gather addresses are load-independent
//   (compiler can pipeline the 15 gathers per point-group).
// blocks [1500,1628): Bt (rot=0 only), two j columns per block.
__global__ __launch_bounds__(256) void prep_kernel(
    const float* __restrict__ mesh, const float* __restrict__ bary,
    const float* __restrict__ kw, const float* __restrict__ interp,
    bf16_t* __restrict__ sig, bf16_t* __restrict__ Bt) {
  __shared__ float sB[960];           // bary for 4 points (sig branch)
  __shared__ float sI[RR * AA * QQ];  // 1600 floats (w2 branch)
  const int bx = blockIdx.x;
  const int tid = threadIdx.x;

  if (bx < SIG_BLOCKS) {
    const int nb = bx * 4;
    const float4* bsrc = (const float4*)(bary + (size_t)nb * (QQ * 6));
    if (tid < 240) ((float4*)sB)[tid] = bsrc[tid];
    __syncthreads();
    const int qi = tid >> 5;        // 0..7
    const int l = tid & 31;         // f = l*4
    for (int nn = 0; nn < 4; ++nn) {
      bf16_t* sn = sig + (size_t)(nb + nn) * KD;
#pragma unroll
      for (int qb = 0; qb < 5; ++qb) {
        const int q = qb * 8 + qi;
        const float* b = sB + nn * 240 + q * 6;  // broadcast LDS reads
        const int i0 = (int)b[0]; const float w0 = b[1];
        const int i1 = (int)b[2]; const float w1 = b[3];
        const int i2 = (int)b[4]; const float w2 = b[5];
        const float4 v0 = *(const float4*)(mesh + (size_t)i0 * FF + l * 4);
        const float4 v1 = *(const float4*)(mesh + (size_t)i1 * FF + l * 4);
        const float4 v2 = *(const float4*)(mesh + (size_t)i2 * FF + l * 4);
        bf16x4 o;
        o[0] = (bf16_t)(w0 * v0.x + w1 * v1.x + w2 * v2.x);
        o[1] = (bf16_t)(w0 * v0.y + w1 * v1.y + w2 * v2.y);
        o[2] = (bf16_t)(w0 * v0.z + w1 * v1.z + w2 * v2.z);
        o[3] = (bf16_t)(w0 * v0.w + w1 * v1.w + w2 * v2.w);
        *(bf16x4*)(sn + q * FF + l * 4) = o;
      }
    }
  } else {
    // ---- w2 (rot=0 only): two j columns per block (128 threads each).
    const int j = (bx - SIG_BLOCKS) * 2 + (tid >> 7);  // 0..255
    const int f = tid & 127;
    for (int i = tid; i < RR * AA * QQ; i += 256) sI[i] = interp[i];
    __syncthreads();
    const int o = (j >> 1) & 127;
    const int k = j & 1;
    float acc[QQ];
#pragma unroll
    for (int q = 0; q < QQ; ++q) acc[q] = 0.f;
    for (int r = 0; r < RR; ++r) {
      for (int a = 0; a < AA; ++a) {
        const float kv =
            kw[((size_t)((r * AA + a) * 2 + k) * OO + o) * FF + f];
        const float4* ip = (const float4*)(sI + (r * AA + a) * QQ);
#pragma unroll
        for (int q4 = 0; q4 < QQ / 4; ++q4) {
          const float4 w4 = ip[q4];
          acc[q4 * 4 + 0] += w4.x * kv;
          acc[q4 * 4 + 1] += w4.y * kv;
          acc[q4 * 4 + 2] += w4.z * kv;
          acc[q4 * 4 + 3] += w4.w * kv;
        }
      }
    }
    bf16_t* bj = Bt + (size_t)j * KD;
#pragma unroll
    for (int q = 0; q < QQ; ++q) bj[q * FF + f] = (bf16_t)acc[q];
  }
}

// ------------------------------------------------- GEMM core (macro body)
// 128x128 tile, BK=64, 4 waves x 4x4 MFMA 16x16x32 bf16, global_load_lds
// width=16, XOR bank swizzle. A k-offset gets the wave-uniform rot-permute:
// q_src = (q & 56) | ((q - rot) & 7)   (BK=64 never straddles a q block).
#define GEMM_CORE(k_lo, k_hi)                                              \
  __shared__ bf16_t As[128 * 64];                                          \
  __shared__ bf16_t Bs[128 * 64];                                          \
  const int tid = threadIdx.x;                                             \
  const int wave = tid >> 6;                                               \
  const int lane = tid & 63;                                               \
  const int quad = lane >> 4;                                              \
  const int tl = lane & 15;                                                \
  const int wm = (wave & 1) * 64;                                          \
  const int wn = (wave >> 1) * 64;                                         \
  const int srow = lane >> 3;                                              \
  const int sc = (lane & 7) ^ srow;                                        \
  f32x4 acc[4][4];                                                         \
  _Pragma("unroll") for (int mm = 0; mm < 4; ++mm)                         \
      _Pragma("unroll") for (int nn = 0; nn < 4; ++nn)                     \
          acc[mm][nn] = {0.f, 0.f, 0.f, 0.f};                              \
  for (int kk = (k_lo); kk < (k_hi); kk += 64) {                           \
    const int qq = kk >> 7;                                                \
    const int akk = (((qq & 56) | ((qq - rot) & 7)) << 7) | (kk & 127);    \
    __syncthreads();                                                       \
    _Pragma("unroll") for (int i = 0; i < 4; ++i) {                        \
      const int row = wave * 32 + i * 8;                                   \
      int gm = m0 + row + srow;                                            \
      gm = gm < N_PTS ? gm : (N_PTS - 1);                                  \
      const int gn = n0 + row + srow;                                      \
      GLOAD_LDS16(Asig + (size_t)gm * KD + akk + sc * 8, As + row * 64);   \
      GLOAD_LDS16(Bt + (size_t)gn * KD + kk + sc * 8, Bs + row * 64);      \
    }                                                                      \
    __syncthreads();                                                       \
    _Pragma("unroll") for (int ks = 0; ks < 2; ++ks) {                     \
      const int ch = (((ks * 4 + quad) ^ (tl & 7)) * 8);                   \
      bf16x8 af[4], bfr[4];                                                \
      _Pragma("unroll") for (int mm = 0; mm < 4; ++mm)                     \
          af[mm] = *(const bf16x8*)(As + (wm + mm * 16 + tl) * 64 + ch);   \
      _Pragma("unroll") for (int nn = 0; nn < 4; ++nn)                     \
          bfr[nn] = *(const bf16x8*)(Bs + (wn + nn * 16 + tl) * 64 + ch);  \
      _Pragma("unroll") for (int mm = 0; mm < 4; ++mm)                     \
          _Pragma("unroll") for (int nn = 0; nn < 4; ++nn)                 \
              acc[mm][nn] = __builtin_amdgcn_mfma_f32_16x16x32_bf16(       \
                  af[mm], bfr[nn], acc[mm][nn], 0, 0, 0);                  \
    }                                                                      \
  }

// --------------------------------------- fused GEMM + bias/relu/fold
// Grid 768: xcd=L&7, t=L>>3 (0..95); slab g = xcd+8*(t>>4): 16 inner blocks
// (8 rot x 2 ncol) share one 128-row sig slab in one XCD's L2; B (2.6 MB)
// L2-resident everywhere.
// Epilogue: v=relu(acc+40*bias[k,o]); lanes (j, j^1) hold (k=0,k=1) of the
// same o -> shfl_xor(1) pair-sum; even lanes store out[m, rot*128+o].
__global__ __launch_bounds__(256) void gemm_fused_kernel(
    const bf16_t* __restrict__ Asig, const bf16_t* __restrict__ Bt,
    const float* __restrict__ bias, float* __restrict__ out) {
  const int L = blockIdx.x;
  const int xcd = L & 7;
  const int t = L >> 3;                // 0..95
  const int g = xcd + 8 * (t >> 4);    // 0..47 sig slab
  const int inner = t & 15;
  const int rot = inner & 7;
  const int n0 = (inner >> 3) * 128;
  const int m0 = g * 128;
  if (m0 >= N_PTS) return;

  GEMM_CORE(0, KD)

#pragma unroll
  for (int nn = 0; nn < 4; ++nn) {
    const int j = n0 + wn + nn * 16 + tl;  // 0..255
    const float bb = 40.0f * bias[((j & 1) << 7) | (j >> 1)];
#pragma unroll
    for (int mm = 0; mm < 4; ++mm) {
      const int mrow = m0 + wm + mm * 16 + quad * 4;
      const f32x4 a = acc[mm][nn];
#pragma unroll
      for (int r = 0; r < 4; ++r) {
        float v = a[r] + bb;
        v = v > 0.f ? v : 0.f;
        const float vs = v + __shfl_xor(v, 1, 64);
        if (((lane & 1) == 0) && (mrow + r < N_PTS))
          out[(size_t)(mrow + r) * 1024 + rot * 128 + (j >> 1)] = vs;
      }
    }
  }
}

extern "C" void kernel_launch(void* const* d_in, const int* in_sizes, int n_in,
                              void* d_out, int out_size, void* d_ws,
                              size_t ws_size, hipStream_t stream) {
  const float* mesh = (const float*)d_in[0];    // (6000,128)
  const float* bary = (const float*)d_in[1];    // (6000,5,8,3,2)
  const float* kw = (const float*)d_in[2];      // (5,8,2,128,128)
  const float* bias = (const float*)d_in[3];    // (2,128)
  const float* interp = (const float*)d_in[4];  // (5,8,40)
  float* out = (float*)d_out;                   // (6000,8,128)

  const size_t sig_bytes = (size_t)N_PTS * KD * 2;  // 61.44 MB
  bf16_t* sig = (bf16_t*)d_ws;
  bf16_t* Bt = (bf16_t*)((char*)d_ws + sig_bytes);  // +2.62 MB = 64.06 MB

  prep_kernel<<<SIG_BLOCKS + W2_BLOCKS, 256, 0, stream>>>(mesh, bary, kw,
                                                          interp, sig, Bt);
  gemm_fused_kernel<<<768, 256, 0, stream>>>(sig, Bt, bias, out);
}